// Round 2
// baseline (1634.862 us; speedup 1.0000x reference)
//
#include <hip/hip_runtime.h>
#include <hip/hip_bf16.h>

typedef __hip_bfloat16 bf16;
typedef unsigned short u16;

static __device__ __forceinline__ float b2f(bf16 v) { return __bfloat162float(v); }

// ---------------- dtype detection ----------------
// If x is f32 data, its low 16-bit halves (even u16 indices) are raw mantissa
// bits -> random bf16 exponents. If any of the first 256 halves has exponent
// >= 0x8F (|v| >= 2^16), the data cannot be bf16 N(0,1) -> flag = 1 (f32 mode).
__global__ void k_detect(const u16* __restrict__ xraw, int* __restrict__ flag) {
    __shared__ int s;
    if (threadIdx.x == 0) s = 0;
    __syncthreads();
    u16 u = xraw[threadIdx.x];
    int e = (u >> 7) & 0xFF;
    if (e >= 0x8F) atomicAdd(&s, 1);
    __syncthreads();
    if (threadIdx.x == 0) flag[0] = (s > 0) ? 1 : 0;
}

// ---------------- degree / normalization ----------------
__global__ void k_init_deg(float* deg, int n) {
    int i = blockIdx.x * blockDim.x + threadIdx.x;
    if (i < n) deg[i] = 1.0f;  // self-loop
}

__global__ void k_count_deg(const int* __restrict__ dst, float* deg, int E) {
    int e = blockIdx.x * blockDim.x + threadIdx.x;
    if (e < E) atomicAdd(&deg[dst[e]], 1.0f);  // exact: integer-valued floats
}

__global__ void k_rsqrt(float* deg, int n) {
    int i = blockIdx.x * blockDim.x + threadIdx.x;
    if (i < n) deg[i] = rsqrtf(deg[i]);
}

// ---------------- per-node matmul, pre-scaled by dis[v] ----------------
// g[v,:] = dis[v] * (in[row] @ W);  acc[v,:] = g[v,:]  (self-loop term, f32)
// EXT: input from external buffer (dtype per flag), no gather (stage 1).
// !EXT: input from internal bf16 act buffer via gather index.
template <int FIN, int FOUT, bool EXT>
__global__ void k_matmul(const void* __restrict__ xin, const int* __restrict__ gidx,
                         const bf16* __restrict__ actin,
                         const void* __restrict__ W, const float* __restrict__ dis,
                         bf16* __restrict__ g, float* __restrict__ acc,
                         const int* __restrict__ flag, int n) {
    __shared__ float Ws[FIN * FOUT];
    const int f32m = flag[0];
    for (int i = threadIdx.x; i < FIN * FOUT; i += blockDim.x)
        Ws[i] = f32m ? ((const float*)W)[i] : b2f(((const bf16*)W)[i]);
    __syncthreads();
    int v = blockIdx.x * blockDim.x + threadIdx.x;
    if (v >= n) return;

    float x[FIN];
    if (EXT) {
        if (f32m) {
            const float* p = (const float*)xin;
            #pragma unroll
            for (int k = 0; k < FIN; k++) x[k] = p[(size_t)v * FIN + k];
        } else {
            const bf16* p = (const bf16*)xin;
            #pragma unroll
            for (int k = 0; k < FIN; k++) x[k] = b2f(p[(size_t)v * FIN + k]);
        }
    } else {
        int row = gidx[v];
        #pragma unroll
        for (int k = 0; k < FIN; k++) x[k] = b2f(actin[(size_t)row * FIN + k]);
    }

    float y[FOUT];
    #pragma unroll
    for (int f = 0; f < FOUT; f++) y[f] = 0.f;
    #pragma unroll
    for (int k = 0; k < FIN; k++) {
        float xk = x[k];
        #pragma unroll
        for (int f = 0; f < FOUT; f++) y[f] = fmaf(xk, Ws[k * FOUT + f], y[f]);
    }

    float dv = dis[v];
    #pragma unroll
    for (int f = 0; f < FOUT; f++) {
        float val = dv * y[f];
        g[(size_t)v * FOUT + f] = __float2bfloat16(val);
        acc[(size_t)v * FOUT + f] = val;   // self term kept in f32
    }
}

// ---------------- edge scatter: acc[dst,:] += g[src,:] ----------------
template <int FOUT>
__global__ void k_scatter(const int* __restrict__ src, const int* __restrict__ dst,
                          const bf16* __restrict__ g, float* __restrict__ acc, int total) {
    int gid = blockIdx.x * blockDim.x + threadIdx.x;
    if (gid >= total) return;
    int e = gid / FOUT;
    int f = gid - e * FOUT;
    atomicAdd(&acc[(size_t)dst[e] * FOUT + f], b2f(g[(size_t)src[e] * FOUT + f]));
}

// ---------------- finalize: act = relu(dis*acc + b) -> bf16 ----------------
template <int FOUT>
__global__ void k_finalize(const float* __restrict__ dis, const void* __restrict__ b,
                           const float* __restrict__ acc, bf16* __restrict__ act,
                           const int* __restrict__ flag, int total) {
    int i = blockIdx.x * blockDim.x + threadIdx.x;
    if (i >= total) return;
    int v = i / FOUT;
    int f = i - v * FOUT;
    float bias = flag[0] ? ((const float*)b)[f] : b2f(((const bf16*)b)[f]);
    float val = fmaf(dis[v], acc[i], bias);
    act[i] = __float2bfloat16(val > 0.f ? val : 0.f);
}

// ---------------- final unpool gather -> out (dtype per flag) ----------------
__global__ void k_gather_out(const bf16* __restrict__ act, const int* __restrict__ idx,
                             void* __restrict__ out, const int* __restrict__ flag, int n) {
    int u = blockIdx.x * blockDim.x + threadIdx.x;
    if (u >= n) return;
    size_t r = (size_t)idx[u];
    float v0 = b2f(act[3 * r + 0]);
    float v1 = b2f(act[3 * r + 1]);
    float v2 = b2f(act[3 * r + 2]);
    if (flag[0]) {
        float* o = (float*)out;
        o[3 * (size_t)u + 0] = v0; o[3 * (size_t)u + 1] = v1; o[3 * (size_t)u + 2] = v2;
    } else {
        bf16* o = (bf16*)out;
        o[3 * (size_t)u + 0] = __float2bfloat16(v0);
        o[3 * (size_t)u + 1] = __float2bfloat16(v1);
        o[3 * (size_t)u + 2] = __float2bfloat16(v2);
    }
}

extern "C" void kernel_launch(void* const* d_in, const int* in_sizes, int n_in,
                              void* d_out, int out_size, void* d_ws, size_t ws_size,
                              hipStream_t stream) {
    const void* x  = d_in[0];
    const void* W1 = d_in[1]; const void* b1 = d_in[2];
    const void* W2 = d_in[3]; const void* b2 = d_in[4];
    const void* W3 = d_in[5]; const void* b3 = d_in[6];
    const void* W4 = d_in[7]; const void* b4 = d_in[8];
    const int* e0  = (const int*)d_in[9];
    const int* up1 = (const int*)d_in[10];
    const int* e1  = (const int*)d_in[11];
    const int* up2 = (const int*)d_in[12];
    const int* e2  = (const int*)d_in[13];
    const int* up3 = (const int*)d_in[14];
    const int* e3  = (const int*)d_in[15];
    const int* up4 = (const int*)d_in[16];

    const int N0 = in_sizes[0] / 3;
    const int N1 = in_sizes[10];
    const int N2 = in_sizes[12];
    const int N3 = in_sizes[14];
    const int N4 = in_sizes[16];
    const int E0 = in_sizes[9] / 2, E1 = in_sizes[11] / 2;
    const int E2 = in_sizes[13] / 2, E3 = in_sizes[15] / 2;

    // capacity for rotating buffers (elements)
    size_t CAP = (size_t)N0 * 32;
    if ((size_t)N1 * 64 > CAP) CAP = (size_t)N1 * 64;
    if ((size_t)N2 * 32 > CAP) CAP = (size_t)N2 * 32;
    if ((size_t)N3 * 3  > CAP) CAP = (size_t)N3 * 3;
    size_t maxN = (size_t)(N3 > N2 ? N3 : N2);
    if ((size_t)N1 > maxN) maxN = N1;
    if ((size_t)N0 > maxN) maxN = N0;

    // workspace layout (~106 MB): flag | D (f32) | ACC (f32) | A0 (bf16) | A1 (bf16)
    char* ws = (char*)d_ws;
    int*   flag = (int*)ws;
    float* D    = (float*)(ws + 256);
    float* ACC  = D + maxN;
    bf16*  A0   = (bf16*)(ACC + CAP);   // g (scatter source)
    bf16*  A1   = A0 + CAP;             // activations

    const int B = 256;
    auto cdiv = [](long long a, long long b) { return (int)((a + b - 1) / b); };

    k_detect<<<1, 256, 0, stream>>>((const u16*)x, flag);

    // ---- stage 1: N0, x @ W1 -> 32
    k_init_deg<<<cdiv(N0, B), B, 0, stream>>>(D, N0);
    k_count_deg<<<cdiv(E0, B), B, 0, stream>>>(e0 + E0, D, E0);
    k_rsqrt<<<cdiv(N0, B), B, 0, stream>>>(D, N0);
    k_matmul<3, 32, true><<<cdiv(N0, B), B, 0, stream>>>(x, nullptr, nullptr, W1, D, A0, ACC, flag, N0);
    k_scatter<32><<<cdiv((long long)E0 * 32, B), B, 0, stream>>>(e0, e0 + E0, A0, ACC, E0 * 32);
    k_finalize<32><<<cdiv((long long)N0 * 32, B), B, 0, stream>>>(D, b1, ACC, A1, flag, N0 * 32);

    // ---- stage 2: N1, act1[up1] @ W2 -> 64
    k_init_deg<<<cdiv(N1, B), B, 0, stream>>>(D, N1);
    k_count_deg<<<cdiv(E1, B), B, 0, stream>>>(e1 + E1, D, E1);
    k_rsqrt<<<cdiv(N1, B), B, 0, stream>>>(D, N1);
    k_matmul<32, 64, false><<<cdiv(N1, B), B, 0, stream>>>(nullptr, up1, A1, W2, D, A0, ACC, flag, N1);
    k_scatter<64><<<cdiv((long long)E1 * 64, B), B, 0, stream>>>(e1, e1 + E1, A0, ACC, E1 * 64);
    k_finalize<64><<<cdiv((long long)N1 * 64, B), B, 0, stream>>>(D, b2, ACC, A1, flag, N1 * 64);

    // ---- stage 3: N2, act2[up2] @ W3 -> 32
    k_init_deg<<<cdiv(N2, B), B, 0, stream>>>(D, N2);
    k_count_deg<<<cdiv(E2, B), B, 0, stream>>>(e2 + E2, D, E2);
    k_rsqrt<<<cdiv(N2, B), B, 0, stream>>>(D, N2);
    k_matmul<64, 32, false><<<cdiv(N2, B), B, 0, stream>>>(nullptr, up2, A1, W3, D, A0, ACC, flag, N2);
    k_scatter<32><<<cdiv((long long)E2 * 32, B), B, 0, stream>>>(e2, e2 + E2, A0, ACC, E2 * 32);
    k_finalize<32><<<cdiv((long long)N2 * 32, B), B, 0, stream>>>(D, b3, ACC, A1, flag, N2 * 32);

    // ---- stage 4: N3, act3[up3] @ W4 -> 3
    k_init_deg<<<cdiv(N3, B), B, 0, stream>>>(D, N3);
    k_count_deg<<<cdiv(E3, B), B, 0, stream>>>(e3 + E3, D, E3);
    k_rsqrt<<<cdiv(N3, B), B, 0, stream>>>(D, N3);
    k_matmul<32, 3, false><<<cdiv(N3, B), B, 0, stream>>>(nullptr, up3, A1, W4, D, A0, ACC, flag, N3);
    k_scatter<3><<<cdiv((long long)E3 * 3, B), B, 0, stream>>>(e3, e3 + E3, A0, ACC, E3 * 3);
    k_finalize<3><<<cdiv((long long)N3 * 3, B), B, 0, stream>>>(D, b4, ACC, A1, flag, N3 * 3);

    // ---- final unpool
    k_gather_out<<<cdiv(N4, B), B, 0, stream>>>(A1, up4, d_out, flag, N4);
}